// Round 1
// baseline (218.196 us; speedup 1.0000x reference)
//
#include <hip/hip_runtime.h>
#include <hip/hip_bf16.h>
#include <cstddef>

#define D_  32
#define N_  1024
#define T_  256
#define NT_ 1280
#define B_  32
#define TI  128   // rows per tile (1024 % 128 == 0 -> tiles never cross s/t boundary)
#define TJ  256   // cols per tile (1024 % 256 == 0)

__device__ __forceinline__ float fast_tanh(float x) {
    // tanh(x) = 1 - 2/(e^{2x}+1).  e^{2x}->inf => 1; ->0 => -1.  No NaN paths.
    float e = __expf(2.0f * x);
    return 1.0f - 2.0f * __builtin_amdgcn_rcpf(e + 1.0f);
}

__global__ __launch_bounds__(256) void mlp_adj_kernel(
    const float* __restrict__ S,  const float* __restrict__ Tn,
    const float* __restrict__ Wr, const float* __restrict__ br,
    const float* __restrict__ Wm, const float* __restrict__ bm,
    float* __restrict__ out)
{
    __shared__ float rowA[TI], rowM[TI], colA[TJ], colM[TJ];

    const int jt = blockIdx.x % (NT_ / TJ);                 // 5 col tiles
    const int it = (blockIdx.x / (NT_ / TJ)) % (NT_ / TI);  // 10 row tiles
    const int b  = blockIdx.x / ((NT_ / TJ) * (NT_ / TI));  // 32 batches
    const int i0 = it * TI, j0 = jt * TJ;
    const int rr = (i0 >= N_);          // row region: 0=spatial, 1=temporal
    const int cc = (j0 >= N_);          // col region
    const int r  = rr ? (cc ? 1 : 3) : (cc ? 2 : 0);  // 0=ss,1=tt,2=st,3=ts

    const float* wrR = Wr + r * 2 * D_;      // row half  [:D]
    const float* wrC = wrR + D_;             // col half  [D:]
    const float* wmR = Wm + r * 2 * D_;
    const float* wmC = wmR + D_;
    const float  brel  = br[r];
    const float  bmask = bm[r];
    const int    tid   = threadIdx.x;

    const float* Xrow = rr ? (Tn + ((size_t)b * T_ + (i0 - N_)) * D_)
                           : (S  + ((size_t)b * N_ +  i0       ) * D_);
    const float* Xcol = cc ? (Tn + ((size_t)b * T_ + (j0 - N_)) * D_)
                           : (S  + ((size_t)b * N_ +  j0       ) * D_);

    // ---- row projections (128 rows, threads 0..127); biases folded in ----
    if (tid < TI) {
        const float4* x  = (const float4*)(Xrow + (size_t)tid * D_);
        const float4* wa = (const float4*)wrR;
        const float4* wq = (const float4*)wmR;
        float aA = brel, aM = bmask;
        #pragma unroll
        for (int k = 0; k < D_ / 4; ++k) {
            float4 xv = x[k], av = wa[k], mv = wq[k];
            aA = fmaf(xv.x, av.x, aA); aM = fmaf(xv.x, mv.x, aM);
            aA = fmaf(xv.y, av.y, aA); aM = fmaf(xv.y, mv.y, aM);
            aA = fmaf(xv.z, av.z, aA); aM = fmaf(xv.z, mv.z, aM);
            aA = fmaf(xv.w, av.w, aA); aM = fmaf(xv.w, mv.w, aM);
        }
        rowA[tid] = aA; rowM[tid] = aM;
    }
    // ---- col projections (256 cols, all threads) ----
    {
        const float4* x  = (const float4*)(Xcol + (size_t)tid * D_);
        const float4* wa = (const float4*)wrC;
        const float4* wq = (const float4*)wmC;
        float aA = 0.f, aM = 0.f;
        #pragma unroll
        for (int k = 0; k < D_ / 4; ++k) {
            float4 xv = x[k], av = wa[k], mv = wq[k];
            aA = fmaf(xv.x, av.x, aA); aM = fmaf(xv.x, mv.x, aM);
            aA = fmaf(xv.y, av.y, aA); aM = fmaf(xv.y, mv.y, aM);
            aA = fmaf(xv.z, av.z, aA); aM = fmaf(xv.z, mv.z, aM);
            aA = fmaf(xv.w, av.w, aA); aM = fmaf(xv.w, mv.w, aM);
        }
        colA[tid] = aA; colM[tid] = aM;
    }
    __syncthreads();

    // ---- epilogue: each thread owns 4 consecutive cols, strides over rows ----
    const int jq = (tid & 63) * 4;   // col offset within tile (wave-contiguous)
    const int rb = tid >> 6;         // wave id 0..3 -> row phase
    const float4 cA = *(const float4*)&colA[jq];
    const float4 cM = *(const float4*)&colM[jq];
    float* outp = out + ((size_t)b * NT_ + i0) * NT_ + j0 + jq;

    for (int i = rb; i < TI; i += 4) {
        const float ra = rowA[i], rm = rowM[i];   // LDS broadcast (uniform per wave)
        float4 o;
        o.x = fast_tanh((ra + cA.x) * fmaxf(rm + cM.x, 0.f));
        o.y = fast_tanh((ra + cA.y) * fmaxf(rm + cM.y, 0.f));
        o.z = fast_tanh((ra + cA.z) * fmaxf(rm + cM.z, 0.f));
        o.w = fast_tanh((ra + cA.w) * fmaxf(rm + cM.w, 0.f));
        *(float4*)(outp + (size_t)i * NT_) = o;   // 64 lanes x 16B = 1KB contiguous
    }
}

extern "C" void kernel_launch(void* const* d_in, const int* in_sizes, int n_in,
                              void* d_out, int out_size, void* d_ws, size_t ws_size,
                              hipStream_t stream) {
    const float* S  = (const float*)d_in[0];  // spatial_nodes [32,1024,32]
    const float* Tn = (const float*)d_in[1];  // temporal_nodes [32,256,32]
    const float* Wr = (const float*)d_in[2];  // W_rel  [4,64]
    const float* br = (const float*)d_in[3];  // b_rel  [4]
    const float* Wm = (const float*)d_in[4];  // W_mask [4,64]
    const float* bm = (const float*)d_in[5];  // b_mask [4]
    float* out = (float*)d_out;               // [32,1280,1280] fp32

    const int grid = B_ * (NT_ / TI) * (NT_ / TJ);  // 32*10*5 = 1600 blocks
    mlp_adj_kernel<<<grid, 256, 0, stream>>>(S, Tn, Wr, br, Wm, bm, out);
}